// Round 6
// baseline (1570.200 us; speedup 1.0000x reference)
//
#include <hip/hip_runtime.h>

#define N_NODES 16384
#define E_EDGES 524288
#define HID 128
#define KP 384      // K' = [ah|ah|al] . [bh|bl|bh]
#define PADK 72     // LDS row stride (elems): 144B = 16B-aligned, uniform banking

typedef __attribute__((ext_vector_type(8))) short bf16x8;
typedef __attribute__((ext_vector_type(4))) float f32x4;

__device__ __forceinline__ unsigned short f2bf(float x) {
    unsigned u = __builtin_bit_cast(unsigned, x);
    u = u + 0x7fff + ((u >> 16) & 1);
    return (unsigned short)(u >> 16);
}
__device__ __forceinline__ float bf2f(unsigned short h) {
    return __builtin_bit_cast(float, (unsigned)h << 16);
}

// ---------------- CSR build ----------------

__global__ __launch_bounds__(256) void k_zero(int* __restrict__ cnt) {
    int i = blockIdx.x * 256 + threadIdx.x;
    if (i < N_NODES) cnt[i] = 0;
}

__global__ __launch_bounds__(256) void k_count(const int* __restrict__ ei, int* __restrict__ cnt) {
    int e = blockIdx.x * 256 + threadIdx.x;
    if (e < E_EDGES) {
        int d = ei[E_EDGES + e];
        atomicAdd(&cnt[d], 1);
    }
}

__global__ __launch_bounds__(1024) void k_scan(const int* __restrict__ cnt, int* __restrict__ rp,
                                               int* __restrict__ cur, float* __restrict__ dinv) {
    __shared__ int part[1024];
    int t = threadIdx.x;
    int base = t * 16;
    int loc[16];
    int s = 0;
#pragma unroll
    for (int i = 0; i < 16; ++i) { loc[i] = cnt[base + i]; s += loc[i]; }
    part[t] = s;
    __syncthreads();
    for (int off = 1; off < 1024; off <<= 1) {
        int add = (t >= off) ? part[t - off] : 0;
        __syncthreads();
        part[t] += add;
        __syncthreads();
    }
    int excl = (t == 0) ? 0 : part[t - 1];
#pragma unroll
    for (int i = 0; i < 16; ++i) {
        rp[base + i] = excl;
        cur[base + i] = excl;
        dinv[base + i] = rsqrtf((float)(loc[i] + 1));  // +1 self-loop
        excl += loc[i];
    }
    if (t == 1023) rp[N_NODES] = excl;
}

__global__ __launch_bounds__(256) void k_fill(const int* __restrict__ ei, int* __restrict__ cur,
                                              int* __restrict__ eidx) {
    int e = blockIdx.x * 256 + threadIdx.x;
    if (e < E_EDGES) {
        int s = ei[e];
        int d = ei[E_EDGES + e];
        int p = atomicAdd(&cur[d], 1);
        eidx[p] = s;
    }
}

// ---------------- layer GEMMs ----------------

__global__ __launch_bounds__(256) void k_gemm16(const float* __restrict__ X, const float* __restrict__ W,
                                                float* __restrict__ T) {
    __shared__ float sW[16 * 128];
    int t = threadIdx.x;
#pragma unroll
    for (int i = 0; i < 8; ++i) sW[i * 256 + t] = W[i * 256 + t];
    __syncthreads();
    int row = blockIdx.x * 2 + (t >> 7);
    int c = t & 127;
    const float* xr = X + row * 16;
    float acc = 0.f;
#pragma unroll
    for (int k = 0; k < 16; ++k) acc = fmaf(xr[k], sW[k * 128 + c], acc);
    T[row * HID + c] = acc;
}

__global__ __launch_bounds__(256) void k_gemm128(const float* __restrict__ A, const float* __restrict__ W,
                                                 float* __restrict__ T) {
    __shared__ float sA[64][132];
    __shared__ float sW[128][132];
    int t = threadIdx.x;
    int bm = blockIdx.x * 64;
#pragma unroll
    for (int it = 0; it < 8; ++it) {
        int f = it * 256 + t;
        int m = f >> 5, k4 = f & 31;
        *(float4*)(&sA[m][k4 * 4]) = *(const float4*)(A + (bm + m) * HID + k4 * 4);
    }
#pragma unroll
    for (int it = 0; it < 16; ++it) {
        int f = it * 256 + t;
        int k = f >> 5, n4 = f & 31;
        *(float4*)(&sW[k][n4 * 4]) = *(const float4*)(W + k * HID + n4 * 4);
    }
    __syncthreads();
    int tx = t & 15, ty = t >> 4;
    float acc[4][8] = {};
    for (int k4 = 0; k4 < 32; ++k4) {
        float4 a[4], b0[4], b1[4];
#pragma unroll
        for (int i = 0; i < 4; ++i) a[i] = *(const float4*)(&sA[ty * 4 + i][k4 * 4]);
#pragma unroll
        for (int kk = 0; kk < 4; ++kk) {
            b0[kk] = *(const float4*)(&sW[k4 * 4 + kk][tx * 4]);
            b1[kk] = *(const float4*)(&sW[k4 * 4 + kk][tx * 4 + 64]);
        }
#pragma unroll
        for (int kk = 0; kk < 4; ++kk) {
#pragma unroll
            for (int i = 0; i < 4; ++i) {
                float av = reinterpret_cast<const float*>(&a[i])[kk];
#pragma unroll
                for (int j = 0; j < 4; ++j) {
                    acc[i][j]     = fmaf(av, reinterpret_cast<const float*>(&b0[kk])[j], acc[i][j]);
                    acc[i][4 + j] = fmaf(av, reinterpret_cast<const float*>(&b1[kk])[j], acc[i][4 + j]);
                }
            }
        }
    }
#pragma unroll
    for (int i = 0; i < 4; ++i) {
        int row = bm + ty * 4 + i;
        float4 o0, o1;
        o0.x = acc[i][0]; o0.y = acc[i][1]; o0.z = acc[i][2]; o0.w = acc[i][3];
        o1.x = acc[i][4]; o1.y = acc[i][5]; o1.z = acc[i][6]; o1.w = acc[i][7];
        *(float4*)(T + row * HID + tx * 4) = o0;
        *(float4*)(T + row * HID + tx * 4 + 64) = o1;
    }
}

// ---------------- aggregation ----------------
__global__ __launch_bounds__(128) void k_agg(const float* __restrict__ T, const int* __restrict__ rp,
                                             const int* __restrict__ eidx, const float* __restrict__ dinv,
                                             const float* __restrict__ b, float* __restrict__ H) {
    __shared__ int se[128];
    __shared__ float sw[128];
    int i = blockIdx.x;
    int c = threadIdx.x;
    float di = dinv[i];
    float acc = di * T[i * HID + c];
    int beg = rp[i], end = rp[i + 1];
    for (int base = beg; base < end; base += 128) {
        int e = base + c;
        if (e < end) {
            int s = eidx[e];
            se[c] = s;
            sw[c] = dinv[s];
        }
        __syncthreads();
        int n = min(128, end - base);
        for (int j = 0; j < n; ++j) {
            acc += sw[j] * T[se[j] * HID + c];
        }
        __syncthreads();
    }
    float v = fmaf(di, acc, b[c]);
    H[i * HID + c] = fmaxf(v, 0.0f);
}

// ---------------- prep: build K'=384 operands ----------------
// A2[r][0:128)=hi, [128:256)=hi, [256:384)=lo
__global__ __launch_bounds__(256) void k_prep_a2(const float* __restrict__ A,
                                                 unsigned short* __restrict__ A2) {
    int idx = (blockIdx.x * 256 + threadIdx.x) * 8;
    int r = idx >> 7, k = idx & 127;
    float4 v0 = *(const float4*)(A + idx);
    float4 v1 = *(const float4*)(A + idx + 4);
    float v[8] = {v0.x, v0.y, v0.z, v0.w, v1.x, v1.y, v1.z, v1.w};
    alignas(16) unsigned short hb[8], lb[8];
#pragma unroll
    for (int j = 0; j < 8; ++j) {
        unsigned short h = f2bf(v[j]);
        hb[j] = h;
        lb[j] = f2bf(v[j] - bf2f(h));
    }
    size_t o = (size_t)r * KP + k;
    *(uint4*)(A2 + o)       = *(uint4*)hb;
    *(uint4*)(A2 + o + 128) = *(uint4*)hb;
    *(uint4*)(A2 + o + 256) = *(uint4*)lb;
}

// B2[n][0:128)=hi, [128:256)=lo, [256:384)=hi  (transposed from Wfc[128][N])
__global__ __launch_bounds__(256) void k_prep_b2(const float* __restrict__ W,
                                                 unsigned short* __restrict__ B2) {
    __shared__ float sm[32][132];
    int t = threadIdx.x;
    int nb = blockIdx.x;   // 0..127
    int kb = blockIdx.y;   // 0..3
#pragma unroll
    for (int i = 0; i < 4; ++i) {
        int idx = i * 256 + t;
        int k = idx >> 5, n4 = idx & 31;
        *(float4*)(&sm[k][n4 * 4]) =
            *(const float4*)(W + (size_t)(kb * 32 + k) * N_NODES + nb * 128 + n4 * 4);
    }
    __syncthreads();
    int n = t >> 1, half = t & 1;
    alignas(16) unsigned short hb[16], lb[16];
#pragma unroll
    for (int j = 0; j < 16; ++j) {
        float x = sm[half * 16 + j][n];
        unsigned short h = f2bf(x);
        hb[j] = h;
        lb[j] = f2bf(x - bf2f(h));
    }
    size_t o = (size_t)(nb * 128 + n) * KP + kb * 32 + half * 16;
    *(uint4*)(B2 + o)           = *(uint4*)hb;
    *(uint4*)(B2 + o + 8)       = *(uint4*)(hb + 8);
    *(uint4*)(B2 + o + 128)     = *(uint4*)lb;
    *(uint4*)(B2 + o + 136)     = *(uint4*)(lb + 8);
    *(uint4*)(B2 + o + 256)     = *(uint4*)hb;
    *(uint4*)(B2 + o + 264)     = *(uint4*)(hb + 8);
}

// ---------------- final FC: m97-style LDS GEMM, C = A2[16384,384] @ B2^T + bias ----------------
// BM=BN=128, 4 waves (2x2), wave tile 64x64, 6 K-steps of BK=64.
// Reg-staged LDS, PAD=72 (16B-aligned b128, uniform banking), prefetch next step
// under current step's MFMAs; 2 barriers/step; stores once at the end.
__global__ __launch_bounds__(256, 3) void k_fc_mfma(const unsigned short* __restrict__ A2,
                                                    const unsigned short* __restrict__ B2,
                                                    const float* __restrict__ bias,
                                                    float* __restrict__ C) {
    __shared__ unsigned short sA[128 * PADK];
    __shared__ unsigned short sB[128 * PADK];
    int t = threadIdx.x;
    int bn = blockIdx.x & 127, bm = blockIdx.x >> 7;
    int wid = t >> 6, lane = t & 63;
    int wm = wid >> 1, wn = wid & 1;
    int row16 = lane & 15, kq = lane >> 4;

    // staging map: thread t + iter i -> row R = (t>>3)+i*32, chunk k8 = t&7
    int sR = t >> 3, sk8 = t & 7;
    const unsigned short* gA = A2 + (size_t)(bm * 128 + sR) * KP + sk8 * 8;
    const unsigned short* gB = B2 + (size_t)(bn * 128 + sR) * KP + sk8 * 8;

    uint4 ga[4], gb[4];
#pragma unroll
    for (int i = 0; i < 4; ++i) {
        ga[i] = *(const uint4*)(gA + (size_t)i * 32 * KP);
        gb[i] = *(const uint4*)(gB + (size_t)i * 32 * KP);
    }

    f32x4 acc[4][4] = {};
#pragma unroll
    for (int s = 0; s < 6; ++s) {
        // write staged regs to LDS (compiler waits the loads here)
#pragma unroll
        for (int i = 0; i < 4; ++i) {
            *(uint4*)(&sA[(sR + i * 32) * PADK + sk8 * 8]) = ga[i];
            *(uint4*)(&sB[(sR + i * 32) * PADK + sk8 * 8]) = gb[i];
        }
        __syncthreads();
        // issue next step's global loads; latency hides under the MFMAs below
        if (s < 5) {
#pragma unroll
            for (int i = 0; i < 4; ++i) {
                ga[i] = *(const uint4*)(gA + (s + 1) * 64 + (size_t)i * 32 * KP);
                gb[i] = *(const uint4*)(gB + (s + 1) * 64 + (size_t)i * 32 * KP);
            }
        }
#pragma unroll
        for (int kk = 0; kk < 2; ++kk) {
            bf16x8 af[4], bf[4];
#pragma unroll
            for (int m = 0; m < 4; ++m)
                af[m] = *(const bf16x8*)(&sA[(wm * 64 + m * 16 + row16) * PADK + kk * 32 + kq * 8]);
#pragma unroll
            for (int n = 0; n < 4; ++n)
                bf[n] = *(const bf16x8*)(&sB[(wn * 64 + n * 16 + row16) * PADK + kk * 32 + kq * 8]);
#pragma unroll
            for (int n = 0; n < 4; ++n)
#pragma unroll
                for (int m = 0; m < 4; ++m)
                    acc[m][n] = __builtin_amdgcn_mfma_f32_16x16x32_bf16(af[m], bf[n], acc[m][n], 0, 0, 0);
        }
        __syncthreads();
    }

    // epilogue: C/D layout col=lane&15, row=(lane>>4)*4+reg  [m89-verified]
    int m0 = bm * 128 + wm * 64;
    int n0 = bn * 128 + wn * 64;
#pragma unroll
    for (int n = 0; n < 4; ++n) {
        int col = n0 + n * 16 + row16;
        float bv = bias[col];
#pragma unroll
        for (int m = 0; m < 4; ++m) {
            int r0 = m0 + m * 16 + kq * 4;
#pragma unroll
            for (int r = 0; r < 4; ++r)
                C[(size_t)(r0 + r) * N_NODES + col] = acc[m][n][r] + bv;
        }
    }
}

// ---------------- launch ----------------

extern "C" void kernel_launch(void* const* d_in, const int* in_sizes, int n_in,
                              void* d_out, int out_size, void* d_ws, size_t ws_size,
                              hipStream_t stream) {
    const float* x   = (const float*)d_in[0];
    const int*   ei  = (const int*)d_in[1];
    const float* W1  = (const float*)d_in[2];
    const float* b1  = (const float*)d_in[3];
    const float* W2  = (const float*)d_in[4];
    const float* b2  = (const float*)d_in[5];
    const float* W3  = (const float*)d_in[6];
    const float* b3  = (const float*)d_in[7];
    const float* Wfc = (const float*)d_in[8];
    const float* bfc = (const float*)d_in[9];
    float* out = (float*)d_out;

    char* ws = (char*)d_ws;
    int* cnt  = (int*)ws;                   // 16384
    int* rp   = cnt + N_NODES;              // 16385 (+pad)
    int* cur  = rp + N_NODES + 64;          // 16384
    int* eidx = cur + N_NODES;              // E
    float* dinv = (float*)(eidx + E_EDGES); // 16384
    float* t  = dinv + N_NODES;             // N*128 fp32
    float* h  = t + N_NODES * HID;          // N*128 fp32
    unsigned short* A2 = (unsigned short*)(h + N_NODES * HID);  // N*384 bf16
    unsigned short* B2 = A2 + (size_t)N_NODES * KP;             // N*384 bf16

    k_zero<<<N_NODES / 256, 256, 0, stream>>>(cnt);
    k_count<<<E_EDGES / 256, 256, 0, stream>>>(ei, cnt);
    k_scan<<<1, 1024, 0, stream>>>(cnt, rp, cur, dinv);
    k_fill<<<E_EDGES / 256, 256, 0, stream>>>(ei, cur, eidx);

    // layers
    k_gemm16<<<N_NODES / 2, 256, 0, stream>>>(x, W1, t);
    k_agg<<<N_NODES, 128, 0, stream>>>(t, rp, eidx, dinv, b1, h);
    k_gemm128<<<N_NODES / 64, 256, 0, stream>>>(h, W2, t);
    k_agg<<<N_NODES, 128, 0, stream>>>(t, rp, eidx, dinv, b2, h);
    k_gemm128<<<N_NODES / 64, 256, 0, stream>>>(h, W3, t);
    k_agg<<<N_NODES, 128, 0, stream>>>(t, rp, eidx, dinv, b3, h);

    // build K'=384 operands
    k_prep_b2<<<dim3(N_NODES / 128, HID / 32), 256, 0, stream>>>(Wfc, B2);
    k_prep_a2<<<(N_NODES * HID) / (256 * 8), 256, 0, stream>>>(h, A2);

    // final FC
    k_fc_mfma<<<N_NODES / 128 * (N_NODES / 128), 256, 0, stream>>>(A2, B2, bfc, out);
}

// Round 9
// 1115.238 us; speedup vs baseline: 1.4080x; 1.4080x over previous
//
#include <hip/hip_runtime.h>

#define N_NODES 16384
#define E_EDGES 524288
#define HID 128

typedef __attribute__((ext_vector_type(8))) short bf16x8;
typedef __attribute__((ext_vector_type(4))) float f32x4;

__device__ __forceinline__ unsigned short f2bf(float x) {
    unsigned u = __builtin_bit_cast(unsigned, x);
    u = u + 0x7fff + ((u >> 16) & 1);
    return (unsigned short)(u >> 16);
}
__device__ __forceinline__ float bf2f(unsigned short h) {
    return __builtin_bit_cast(float, (unsigned)h << 16);
}

// ---------------- CSR build ----------------

__global__ __launch_bounds__(256) void k_zero(int* __restrict__ cnt) {
    int i = blockIdx.x * 256 + threadIdx.x;
    if (i < N_NODES) cnt[i] = 0;
}

__global__ __launch_bounds__(256) void k_count(const int* __restrict__ ei, int* __restrict__ cnt) {
    int e = blockIdx.x * 256 + threadIdx.x;
    if (e < E_EDGES) {
        int d = ei[E_EDGES + e];
        atomicAdd(&cnt[d], 1);
    }
}

__global__ __launch_bounds__(1024) void k_scan(const int* __restrict__ cnt, int* __restrict__ rp,
                                               int* __restrict__ cur, float* __restrict__ dinv) {
    __shared__ int part[1024];
    int t = threadIdx.x;
    int base = t * 16;
    int loc[16];
    int s = 0;
#pragma unroll
    for (int i = 0; i < 16; ++i) { loc[i] = cnt[base + i]; s += loc[i]; }
    part[t] = s;
    __syncthreads();
    for (int off = 1; off < 1024; off <<= 1) {
        int add = (t >= off) ? part[t - off] : 0;
        __syncthreads();
        part[t] += add;
        __syncthreads();
    }
    int excl = (t == 0) ? 0 : part[t - 1];
#pragma unroll
    for (int i = 0; i < 16; ++i) {
        rp[base + i] = excl;
        cur[base + i] = excl;
        dinv[base + i] = rsqrtf((float)(loc[i] + 1));  // +1 self-loop
        excl += loc[i];
    }
    if (t == 1023) rp[N_NODES] = excl;
}

__global__ __launch_bounds__(256) void k_fill(const int* __restrict__ ei, int* __restrict__ cur,
                                              int* __restrict__ eidx) {
    int e = blockIdx.x * 256 + threadIdx.x;
    if (e < E_EDGES) {
        int s = ei[e];
        int d = ei[E_EDGES + e];
        int p = atomicAdd(&cur[d], 1);
        eidx[p] = s;
    }
}

// ---------------- layer GEMMs ----------------

__global__ __launch_bounds__(256) void k_gemm16(const float* __restrict__ X, const float* __restrict__ W,
                                                float* __restrict__ T) {
    __shared__ float sW[16 * 128];
    int t = threadIdx.x;
#pragma unroll
    for (int i = 0; i < 8; ++i) sW[i * 256 + t] = W[i * 256 + t];
    __syncthreads();
    int row = blockIdx.x * 2 + (t >> 7);
    int c = t & 127;
    const float* xr = X + row * 16;
    float acc = 0.f;
#pragma unroll
    for (int k = 0; k < 16; ++k) acc = fmaf(xr[k], sW[k * 128 + c], acc);
    T[row * HID + c] = acc;
}

__global__ __launch_bounds__(256) void k_gemm128(const float* __restrict__ A, const float* __restrict__ W,
                                                 float* __restrict__ T) {
    __shared__ float sA[64][132];
    __shared__ float sW[128][132];
    int t = threadIdx.x;
    int bm = blockIdx.x * 64;
#pragma unroll
    for (int it = 0; it < 8; ++it) {
        int f = it * 256 + t;
        int m = f >> 5, k4 = f & 31;
        *(float4*)(&sA[m][k4 * 4]) = *(const float4*)(A + (bm + m) * HID + k4 * 4);
    }
#pragma unroll
    for (int it = 0; it < 16; ++it) {
        int f = it * 256 + t;
        int k = f >> 5, n4 = f & 31;
        *(float4*)(&sW[k][n4 * 4]) = *(const float4*)(W + k * HID + n4 * 4);
    }
    __syncthreads();
    int tx = t & 15, ty = t >> 4;
    float acc[4][8] = {};
    for (int k4 = 0; k4 < 32; ++k4) {
        float4 a[4], b0[4], b1[4];
#pragma unroll
        for (int i = 0; i < 4; ++i) a[i] = *(const float4*)(&sA[ty * 4 + i][k4 * 4]);
#pragma unroll
        for (int kk = 0; kk < 4; ++kk) {
            b0[kk] = *(const float4*)(&sW[k4 * 4 + kk][tx * 4]);
            b1[kk] = *(const float4*)(&sW[k4 * 4 + kk][tx * 4 + 64]);
        }
#pragma unroll
        for (int kk = 0; kk < 4; ++kk) {
#pragma unroll
            for (int i = 0; i < 4; ++i) {
                float av = reinterpret_cast<const float*>(&a[i])[kk];
#pragma unroll
                for (int j = 0; j < 4; ++j) {
                    acc[i][j]     = fmaf(av, reinterpret_cast<const float*>(&b0[kk])[j], acc[i][j]);
                    acc[i][4 + j] = fmaf(av, reinterpret_cast<const float*>(&b1[kk])[j], acc[i][4 + j]);
                }
            }
        }
    }
#pragma unroll
    for (int i = 0; i < 4; ++i) {
        int row = bm + ty * 4 + i;
        float4 o0, o1;
        o0.x = acc[i][0]; o0.y = acc[i][1]; o0.z = acc[i][2]; o0.w = acc[i][3];
        o1.x = acc[i][4]; o1.y = acc[i][5]; o1.z = acc[i][6]; o1.w = acc[i][7];
        *(float4*)(T + row * HID + tx * 4) = o0;
        *(float4*)(T + row * HID + tx * 4 + 64) = o1;
    }
}

// ---------------- aggregation ----------------
__global__ __launch_bounds__(128) void k_agg(const float* __restrict__ T, const int* __restrict__ rp,
                                             const int* __restrict__ eidx, const float* __restrict__ dinv,
                                             const float* __restrict__ b, float* __restrict__ H) {
    __shared__ int se[128];
    __shared__ float sw[128];
    int i = blockIdx.x;
    int c = threadIdx.x;
    float di = dinv[i];
    float acc = di * T[i * HID + c];
    int beg = rp[i], end = rp[i + 1];
    for (int base = beg; base < end; base += 128) {
        int e = base + c;
        if (e < end) {
            int s = eidx[e];
            se[c] = s;
            sw[c] = dinv[s];
        }
        __syncthreads();
        int n = min(128, end - base);
        for (int j = 0; j < n; ++j) {
            acc += sw[j] * T[se[j] * HID + c];
        }
        __syncthreads();
    }
    float v = fmaf(di, acc, b[c]);
    H[i * HID + c] = fmaxf(v, 0.0f);
}

// ---------------- bf16 split prep (R5-verified versions) ----------------

__global__ __launch_bounds__(256) void k_split_a(const float* __restrict__ A,
                                                 unsigned short* __restrict__ hi,
                                                 unsigned short* __restrict__ lo) {
    int i = (blockIdx.x * 256 + threadIdx.x) * 8;
    float4 v0 = *(const float4*)(A + i);
    float4 v1 = *(const float4*)(A + i + 4);
    float v[8] = {v0.x, v0.y, v0.z, v0.w, v1.x, v1.y, v1.z, v1.w};
    alignas(16) unsigned short hb[8], lb[8];
#pragma unroll
    for (int j = 0; j < 8; ++j) {
        unsigned short h = f2bf(v[j]);
        hb[j] = h;
        lb[j] = f2bf(v[j] - bf2f(h));
    }
    *(uint4*)(hi + i) = *(uint4*)hb;
    *(uint4*)(lo + i) = *(uint4*)lb;
}

// W[128, N] fp32 -> transposed hi/lo bf16 [N,128] (K contiguous)
__global__ __launch_bounds__(256) void k_split_b(const float* __restrict__ W,
                                                 unsigned short* __restrict__ bhi,
                                                 unsigned short* __restrict__ blo) {
    __shared__ float sm[32][132];
    int t = threadIdx.x;
    int nb = blockIdx.x;   // 0..127
    int kb = blockIdx.y;   // 0..3
#pragma unroll
    for (int i = 0; i < 4; ++i) {
        int idx = i * 256 + t;
        int k = idx >> 5, n4 = idx & 31;
        *(float4*)(&sm[k][n4 * 4]) =
            *(const float4*)(W + (size_t)(kb * 32 + k) * N_NODES + nb * 128 + n4 * 4);
    }
    __syncthreads();
    int n = t >> 1, half = t & 1;
    alignas(16) unsigned short hb[16], lb[16];
#pragma unroll
    for (int j = 0; j < 16; ++j) {
        float x = sm[half * 16 + j][n];
        unsigned short h = f2bf(x);
        hb[j] = h;
        lb[j] = f2bf(x - bf2f(h));
    }
    size_t o = (size_t)(nb * 128 + n) * 128 + kb * 32 + half * 16;
    *(uint4*)(bhi + o) = *(uint4*)hb;
    *(uint4*)(bhi + o + 8) = *(uint4*)(hb + 8);
    *(uint4*)(blo + o) = *(uint4*)lb;
    *(uint4*)(blo + o + 8) = *(uint4*)(lb + 8);
}

// ---------------- final FC via MFMA, split-bf16, swapped-operand epilogue ----------------
// C[16384,16384] = A[16384,128] @ Wfc[128,16384] + bias
// acc[m][n] = mfma(B_frag[n], A_frag[m], acc): by the m89-verified C/D mapping
// (col=lane&15 indexes the SECOND operand's row set, row=(lane>>4)*4+reg the first),
// each lane then holds C[m*16+row16][n*16+kq*4 + r] for r=0..3 — 4 consecutive
// columns of a lane-fixed row -> direct float4 stores, NO LDS transpose, no
// cross-lane exchange (R7/R8's bug), no partial-line write-allocate (R6's bug).
__global__ __launch_bounds__(256) void k_fc_mfma(const unsigned short* __restrict__ Ahi,
                                                 const unsigned short* __restrict__ Alo,
                                                 const unsigned short* __restrict__ Bhi,
                                                 const unsigned short* __restrict__ Blo,
                                                 const float* __restrict__ bias,
                                                 float* __restrict__ C) {
    int t = threadIdx.x;
    int wid = t >> 6, lane = t & 63;
    int row16 = lane & 15, kq = lane >> 4;
    int m0 = (blockIdx.x >> 3) * 256 + wid * 64;   // wave's 64-row stripe
    int colbase = (blockIdx.x & 7) * 2048;         // col stripe

    const unsigned short* pah = Ahi + (size_t)(m0 + row16) * HID + kq * 8;
    const unsigned short* pal = Alo + (size_t)(m0 + row16) * HID + kq * 8;

    // persistent A ks0 fragments (loop-invariant)
    bf16x8 ah0[4], al0[4];
#pragma unroll
    for (int m = 0; m < 4; ++m) {
        ah0[m] = *(const bf16x8*)(pah + m * 16 * HID);
        al0[m] = *(const bf16x8*)(pal + m * 16 * HID);
    }

    // prefetch B ks0 for it=0
    bf16x8 pfbh[4], pfbl[4];
    {
        const unsigned short* pbh0 = Bhi + (size_t)(colbase + row16) * HID + kq * 8;
        const unsigned short* pbl0 = Blo + (size_t)(colbase + row16) * HID + kq * 8;
#pragma unroll
        for (int n = 0; n < 4; ++n) {
            pfbh[n] = *(const bf16x8*)(pbh0 + n * 16 * HID);
            pfbl[n] = *(const bf16x8*)(pbl0 + n * 16 * HID);
        }
    }

    for (int it = 0; it < 32; ++it) {
        int n0 = colbase + it * 64;
        const unsigned short* pbh = Bhi + (size_t)(n0 + row16) * HID + kq * 8;
        const unsigned short* pbl = Blo + (size_t)(n0 + row16) * HID + kq * 8;

        f32x4 acc[4][4] = {};

        // ks = 0: persistent A, prefetched B — no loads on the critical path
#pragma unroll
        for (int n = 0; n < 4; ++n) {
#pragma unroll
            for (int m = 0; m < 4; ++m)
                acc[m][n] = __builtin_amdgcn_mfma_f32_16x16x32_bf16(pfbh[n], ah0[m], acc[m][n], 0, 0, 0);
#pragma unroll
            for (int m = 0; m < 4; ++m)
                acc[m][n] = __builtin_amdgcn_mfma_f32_16x16x32_bf16(pfbl[n], ah0[m], acc[m][n], 0, 0, 0);
#pragma unroll
            for (int m = 0; m < 4; ++m)
                acc[m][n] = __builtin_amdgcn_mfma_f32_16x16x32_bf16(pfbh[n], al0[m], acc[m][n], 0, 0, 0);
        }
        // ks = 1..3
#pragma unroll
        for (int ks = 1; ks < 4; ++ks) {
            bf16x8 ah[4], al[4], bh[4], bl[4];
#pragma unroll
            for (int m = 0; m < 4; ++m) {
                ah[m] = *(const bf16x8*)(pah + m * 16 * HID + ks * 32);
                al[m] = *(const bf16x8*)(pal + m * 16 * HID + ks * 32);
            }
#pragma unroll
            for (int n = 0; n < 4; ++n) {
                bh[n] = *(const bf16x8*)(pbh + n * 16 * HID + ks * 32);
                bl[n] = *(const bf16x8*)(pbl + n * 16 * HID + ks * 32);
            }
#pragma unroll
            for (int n = 0; n < 4; ++n) {
#pragma unroll
                for (int m = 0; m < 4; ++m)
                    acc[m][n] = __builtin_amdgcn_mfma_f32_16x16x32_bf16(bh[n], ah[m], acc[m][n], 0, 0, 0);
#pragma unroll
                for (int m = 0; m < 4; ++m)
                    acc[m][n] = __builtin_amdgcn_mfma_f32_16x16x32_bf16(bl[n], ah[m], acc[m][n], 0, 0, 0);
#pragma unroll
                for (int m = 0; m < 4; ++m)
                    acc[m][n] = __builtin_amdgcn_mfma_f32_16x16x32_bf16(bh[n], al[m], acc[m][n], 0, 0, 0);
            }
        }

        // prefetch next iter's ks0 B BEFORE the stores (FIFO vmcnt decoupling)
        if (it < 31) {
#pragma unroll
            for (int n = 0; n < 4; ++n) {
                pfbh[n] = *(const bf16x8*)(pbh + 64 * HID + n * 16 * HID);
                pfbl[n] = *(const bf16x8*)(pbl + 64 * HID + n * 16 * HID);
            }
        }

        // epilogue: direct full-sector stores, lane-local data only
#pragma unroll
        for (int m = 0; m < 4; ++m) {
            size_t crow = (size_t)(m0 + m * 16 + row16) * N_NODES + n0;
#pragma unroll
            for (int n = 0; n < 4; ++n) {
                float4 bv = *(const float4*)(bias + n0 + n * 16 + kq * 4);
                float4 v;
                v.x = acc[m][n][0] + bv.x;
                v.y = acc[m][n][1] + bv.y;
                v.z = acc[m][n][2] + bv.z;
                v.w = acc[m][n][3] + bv.w;
                *(float4*)(C + crow + n * 16 + kq * 4) = v;
            }
        }
    }
}

// ---------------- launch ----------------

extern "C" void kernel_launch(void* const* d_in, const int* in_sizes, int n_in,
                              void* d_out, int out_size, void* d_ws, size_t ws_size,
                              hipStream_t stream) {
    const float* x   = (const float*)d_in[0];
    const int*   ei  = (const int*)d_in[1];
    const float* W1  = (const float*)d_in[2];
    const float* b1  = (const float*)d_in[3];
    const float* W2  = (const float*)d_in[4];
    const float* b2  = (const float*)d_in[5];
    const float* W3  = (const float*)d_in[6];
    const float* b3  = (const float*)d_in[7];
    const float* Wfc = (const float*)d_in[8];
    const float* bfc = (const float*)d_in[9];
    float* out = (float*)d_out;

    char* ws = (char*)d_ws;
    int* cnt  = (int*)ws;                   // 16384
    int* rp   = cnt + N_NODES;              // 16385 (+pad)
    int* cur  = rp + N_NODES + 64;          // 16384
    int* eidx = cur + N_NODES;              // E
    float* dinv = (float*)(eidx + E_EDGES); // 16384
    float* t  = dinv + N_NODES;             // N*128 fp32
    float* h  = t + N_NODES * HID;          // N*128 fp32
    unsigned short* ahi = (unsigned short*)t;            // N*128 bf16 (t dead after last agg)
    unsigned short* alo = ahi + (size_t)N_NODES * HID;
    unsigned short* bhi = (unsigned short*)(h + (size_t)N_NODES * HID);
    unsigned short* blo = bhi + (size_t)N_NODES * HID;

    k_zero<<<N_NODES / 256, 256, 0, stream>>>(cnt);
    k_count<<<E_EDGES / 256, 256, 0, stream>>>(ei, cnt);
    k_scan<<<1, 1024, 0, stream>>>(cnt, rp, cur, dinv);
    k_fill<<<E_EDGES / 256, 256, 0, stream>>>(ei, cur, eidx);

    // layers
    k_gemm16<<<N_NODES / 2, 256, 0, stream>>>(x, W1, t);
    k_agg<<<N_NODES, 128, 0, stream>>>(t, rp, eidx, dinv, b1, h);
    k_gemm128<<<N_NODES / 64, 256, 0, stream>>>(h, W2, t);
    k_agg<<<N_NODES, 128, 0, stream>>>(t, rp, eidx, dinv, b2, h);
    k_gemm128<<<N_NODES / 64, 256, 0, stream>>>(h, W3, t);
    k_agg<<<N_NODES, 128, 0, stream>>>(t, rp, eidx, dinv, b3, h);

    // FC prep: split h and Wfc^T into bf16 hi/lo (R5-verified kernels)
    k_split_b<<<dim3(N_NODES / 128, HID / 32), 256, 0, stream>>>(Wfc, bhi, blo);
    k_split_a<<<(N_NODES * HID) / (256 * 8), 256, 0, stream>>>(h, ahi, alo);

    // final FC: 512 blocks (2/CU)
    k_fc_mfma<<<512, 256, 0, stream>>>(ahi, alo, bhi, blo, bfc, out);
}

// Round 10
// 767.133 us; speedup vs baseline: 2.0468x; 1.4538x over previous
//
#include <hip/hip_runtime.h>

#define N_NODES 16384
#define E_EDGES 524288
#define HID 128

typedef __attribute__((ext_vector_type(8))) short bf16x8;
typedef __attribute__((ext_vector_type(4))) float f32x4;

__device__ __forceinline__ unsigned short f2bf(float x) {
    unsigned u = __builtin_bit_cast(unsigned, x);
    u = u + 0x7fff + ((u >> 16) & 1);
    return (unsigned short)(u >> 16);
}
__device__ __forceinline__ float bf2f(unsigned short h) {
    return __builtin_bit_cast(float, (unsigned)h << 16);
}

// ---------------- CSR build ----------------

__global__ __launch_bounds__(256) void k_zero(int* __restrict__ cnt) {
    int i = blockIdx.x * 256 + threadIdx.x;
    if (i < N_NODES) cnt[i] = 0;
}

__global__ __launch_bounds__(256) void k_count(const int* __restrict__ ei, int* __restrict__ cnt) {
    int e = blockIdx.x * 256 + threadIdx.x;
    if (e < E_EDGES) {
        int d = ei[E_EDGES + e];
        atomicAdd(&cnt[d], 1);
    }
}

__global__ __launch_bounds__(1024) void k_scan(const int* __restrict__ cnt, int* __restrict__ rp,
                                               int* __restrict__ cur, float* __restrict__ dinv) {
    __shared__ int part[1024];
    int t = threadIdx.x;
    int base = t * 16;
    int loc[16];
    int s = 0;
#pragma unroll
    for (int i = 0; i < 16; ++i) { loc[i] = cnt[base + i]; s += loc[i]; }
    part[t] = s;
    __syncthreads();
    for (int off = 1; off < 1024; off <<= 1) {
        int add = (t >= off) ? part[t - off] : 0;
        __syncthreads();
        part[t] += add;
        __syncthreads();
    }
    int excl = (t == 0) ? 0 : part[t - 1];
#pragma unroll
    for (int i = 0; i < 16; ++i) {
        rp[base + i] = excl;
        cur[base + i] = excl;
        dinv[base + i] = rsqrtf((float)(loc[i] + 1));  // +1 self-loop
        excl += loc[i];
    }
    if (t == 1023) rp[N_NODES] = excl;
}

__global__ __launch_bounds__(256) void k_fill(const int* __restrict__ ei, int* __restrict__ cur,
                                              int* __restrict__ eidx) {
    int e = blockIdx.x * 256 + threadIdx.x;
    if (e < E_EDGES) {
        int s = ei[e];
        int d = ei[E_EDGES + e];
        int p = atomicAdd(&cur[d], 1);
        eidx[p] = s;
    }
}

// ---------------- layer GEMMs ----------------

__global__ __launch_bounds__(256) void k_gemm16(const float* __restrict__ X, const float* __restrict__ W,
                                                float* __restrict__ T) {
    __shared__ float sW[16 * 128];
    int t = threadIdx.x;
#pragma unroll
    for (int i = 0; i < 8; ++i) sW[i * 256 + t] = W[i * 256 + t];
    __syncthreads();
    int row = blockIdx.x * 2 + (t >> 7);
    int c = t & 127;
    const float* xr = X + row * 16;
    float acc = 0.f;
#pragma unroll
    for (int k = 0; k < 16; ++k) acc = fmaf(xr[k], sW[k * 128 + c], acc);
    T[row * HID + c] = acc;
}

__global__ __launch_bounds__(256) void k_gemm128(const float* __restrict__ A, const float* __restrict__ W,
                                                 float* __restrict__ T) {
    __shared__ float sA[64][132];
    __shared__ float sW[128][132];
    int t = threadIdx.x;
    int bm = blockIdx.x * 64;
#pragma unroll
    for (int it = 0; it < 8; ++it) {
        int f = it * 256 + t;
        int m = f >> 5, k4 = f & 31;
        *(float4*)(&sA[m][k4 * 4]) = *(const float4*)(A + (bm + m) * HID + k4 * 4);
    }
#pragma unroll
    for (int it = 0; it < 16; ++it) {
        int f = it * 256 + t;
        int k = f >> 5, n4 = f & 31;
        *(float4*)(&sW[k][n4 * 4]) = *(const float4*)(W + k * HID + n4 * 4);
    }
    __syncthreads();
    int tx = t & 15, ty = t >> 4;
    float acc[4][8] = {};
    for (int k4 = 0; k4 < 32; ++k4) {
        float4 a[4], b0[4], b1[4];
#pragma unroll
        for (int i = 0; i < 4; ++i) a[i] = *(const float4*)(&sA[ty * 4 + i][k4 * 4]);
#pragma unroll
        for (int kk = 0; kk < 4; ++kk) {
            b0[kk] = *(const float4*)(&sW[k4 * 4 + kk][tx * 4]);
            b1[kk] = *(const float4*)(&sW[k4 * 4 + kk][tx * 4 + 64]);
        }
#pragma unroll
        for (int kk = 0; kk < 4; ++kk) {
#pragma unroll
            for (int i = 0; i < 4; ++i) {
                float av = reinterpret_cast<const float*>(&a[i])[kk];
#pragma unroll
                for (int j = 0; j < 4; ++j) {
                    acc[i][j]     = fmaf(av, reinterpret_cast<const float*>(&b0[kk])[j], acc[i][j]);
                    acc[i][4 + j] = fmaf(av, reinterpret_cast<const float*>(&b1[kk])[j], acc[i][4 + j]);
                }
            }
        }
    }
#pragma unroll
    for (int i = 0; i < 4; ++i) {
        int row = bm + ty * 4 + i;
        float4 o0, o1;
        o0.x = acc[i][0]; o0.y = acc[i][1]; o0.z = acc[i][2]; o0.w = acc[i][3];
        o1.x = acc[i][4]; o1.y = acc[i][5]; o1.z = acc[i][6]; o1.w = acc[i][7];
        *(float4*)(T + row * HID + tx * 4) = o0;
        *(float4*)(T + row * HID + tx * 4 + 64) = o1;
    }
}

// ---------------- aggregation ----------------
__global__ __launch_bounds__(128) void k_agg(const float* __restrict__ T, const int* __restrict__ rp,
                                             const int* __restrict__ eidx, const float* __restrict__ dinv,
                                             const float* __restrict__ b, float* __restrict__ H) {
    __shared__ int se[128];
    __shared__ float sw[128];
    int i = blockIdx.x;
    int c = threadIdx.x;
    float di = dinv[i];
    float acc = di * T[i * HID + c];
    int beg = rp[i], end = rp[i + 1];
    for (int base = beg; base < end; base += 128) {
        int e = base + c;
        if (e < end) {
            int s = eidx[e];
            se[c] = s;
            sw[c] = dinv[s];
        }
        __syncthreads();
        int n = min(128, end - base);
        for (int j = 0; j < n; ++j) {
            acc += sw[j] * T[se[j] * HID + c];
        }
        __syncthreads();
    }
    float v = fmaf(di, acc, b[c]);
    H[i * HID + c] = fmaxf(v, 0.0f);
}

// ---------------- prep: fragment-packed hi/lo operands ----------------
// Packed block layout (32 KB per 64-row/col tile):
//   elem off(comp,f,ks,kq,row16,j) = (((comp*4+f)*4+ks)*4+kq)*128 + row16*8 + j
// comp: 0=hi 1=lo; f: 16-row/col frag index; ks: k-slice (32); kq: k-quarter (8); j: 0..7.
// A fragment/staging read then = base + kq*128 + row16*8 -> contiguous 1 KB per wave.

// A[N,128] f32 -> Ap packed per 64-row tile (at = 0..255)
__global__ __launch_bounds__(256) void k_prep_a(const float* __restrict__ A,
                                                unsigned short* __restrict__ Ap) {
    __shared__ float sm[64][132];
    int t = threadIdx.x;
    int at = blockIdx.x;
#pragma unroll
    for (int i = 0; i < 8; ++i) {
        int idx = i * 256 + t;            // 2048 float4
        int r = idx >> 5, k4 = idx & 31;
        *(float4*)(&sm[r][k4 * 4]) = *(const float4*)(A + (size_t)(at * 64 + r) * HID + k4 * 4);
    }
    __syncthreads();
#pragma unroll
    for (int i = 0; i < 8; ++i) {
        int cg = i * 256 + t;             // 2048 chunks of 8 elems
        int comp = cg >> 10;
        int m = (cg >> 8) & 3;
        int ks = (cg >> 6) & 3;
        int kq = (cg >> 4) & 3;
        int row16 = cg & 15;
        alignas(16) unsigned short ob[8];
#pragma unroll
        for (int j = 0; j < 8; ++j) {
            float x = sm[m * 16 + row16][ks * 32 + kq * 8 + j];
            unsigned short h = f2bf(x);
            ob[j] = comp ? f2bf(x - bf2f(h)) : h;
        }
        *(uint4*)(Ap + (size_t)at * 16384 + cg * 8) = *(uint4*)ob;
    }
}

// Wfc[128,N] f32 -> Bp packed per 64-col tile (ct = 0..255)
__global__ __launch_bounds__(256) void k_prep_b(const float* __restrict__ W,
                                                unsigned short* __restrict__ Bp) {
    __shared__ float sm[128][68];
    int t = threadIdx.x;
    int ct = blockIdx.x;
#pragma unroll
    for (int i = 0; i < 8; ++i) {
        int idx = i * 256 + t;            // 2048 float4
        int k = idx >> 4, c4 = idx & 15;  // 16 float4 per k-row (64 cols)
        *(float4*)(&sm[k][c4 * 4]) = *(const float4*)(W + (size_t)k * N_NODES + ct * 64 + c4 * 4);
    }
    __syncthreads();
#pragma unroll
    for (int i = 0; i < 8; ++i) {
        int cg = i * 256 + t;
        int comp = cg >> 10;
        int n = (cg >> 8) & 3;
        int ks = (cg >> 6) & 3;
        int kq = (cg >> 4) & 3;
        int row16 = cg & 15;
        alignas(16) unsigned short ob[8];
#pragma unroll
        for (int j = 0; j < 8; ++j) {
            float x = sm[ks * 32 + kq * 8 + j][n * 16 + row16];
            unsigned short h = f2bf(x);
            ob[j] = comp ? f2bf(x - bf2f(h)) : h;
        }
        *(uint4*)(Bp + (size_t)ct * 16384 + cg * 8) = *(uint4*)ob;
    }
}

// ---------------- final FC: reg-A + LDS-dbuf-B via global_load_lds ----------------
__device__ __forceinline__ void gload_lds16(const unsigned short* g, unsigned short* l) {
    __builtin_amdgcn_global_load_lds(
        (const __attribute__((address_space(1))) void*)g,
        (__attribute__((address_space(3))) void*)l, 16, 0, 0);
}

// C[16384,16384] = A[16384,128] @ Wfc[128,16384] + bias
// 512 blocks (2/CU): block = 256 rows (4 waves x 64) x 2048-col XCD stripe.
// A hi/lo fragments register-resident (loaded once, packed 1KB wave reads).
// B tiles (64 cols, 32 KB hi+lo) double-buffered in LDS via global_load_lds;
// stage for it+1 issued right after the barrier, hides under 192 MFMAs.
// Epilogue: R9-verified swapped-operand direct float4 stores.
__global__ __launch_bounds__(256, 2) void k_fc_mfma(const unsigned short* __restrict__ Ap,
                                                    const unsigned short* __restrict__ Bp,
                                                    const float* __restrict__ bias,
                                                    float* __restrict__ C) {
    __shared__ unsigned short sB[2][16384];
    int t = threadIdx.x;
    int wid = t >> 6, lane = t & 63;
    int row16 = lane & 15, kq = lane >> 4;
    int mblk = blockIdx.x >> 3;
    int xcd = blockIdx.x & 7;
    int m0 = mblk * 256 + wid * 64;
    int ct0 = xcd * 32;

    // persistent A fragments: 32 x bf16x8 = 128 VGPR
    const unsigned short* ab = Ap + (size_t)(mblk * 4 + wid) * 16384 + kq * 128 + row16 * 8;
    bf16x8 ah[4][4], al[4][4];
#pragma unroll
    for (int m = 0; m < 4; ++m)
#pragma unroll
        for (int ks = 0; ks < 4; ++ks) {
            ah[m][ks] = *(const bf16x8*)(ab + ((0 * 4 + m) * 4 + ks) * 512);
            al[m][ks] = *(const bf16x8*)(ab + ((1 * 4 + m) * 4 + ks) * 512);
        }

    // stage first tile into buf 0
    {
        const unsigned short* g = Bp + (size_t)ct0 * 16384 + (wid * 8) * 512 + lane * 8;
        unsigned short* l = &sB[0][(wid * 8) * 512];
#pragma unroll
        for (int i = 0; i < 8; ++i) gload_lds16(g + i * 512, l + i * 512);
    }

    for (int it = 0; it < 32; ++it) {
        int buf = it & 1;
        __syncthreads();   // drains my gload_lds deposits (and stores); tile `it` ready

        if (it + 1 < 32) {
            const unsigned short* g = Bp + (size_t)(ct0 + it + 1) * 16384 + (wid * 8) * 512 + lane * 8;
            unsigned short* l = &sB[buf ^ 1][(wid * 8) * 512];
#pragma unroll
            for (int i = 0; i < 8; ++i) gload_lds16(g + i * 512, l + i * 512);
        }

        int n0 = xcd * 2048 + it * 64;
        const unsigned short* bb = &sB[buf][kq * 128 + row16 * 8];

        f32x4 acc[4][4] = {};
#pragma unroll
        for (int ks = 0; ks < 4; ++ks) {
            bf16x8 bh[4], bl[4];
#pragma unroll
            for (int n = 0; n < 4; ++n) {
                bh[n] = *(const bf16x8*)(bb + ((0 * 4 + n) * 4 + ks) * 512);
                bl[n] = *(const bf16x8*)(bb + ((1 * 4 + n) * 4 + ks) * 512);
            }
#pragma unroll
            for (int n = 0; n < 4; ++n) {
#pragma unroll
                for (int m = 0; m < 4; ++m)
                    acc[m][n] = __builtin_amdgcn_mfma_f32_16x16x32_bf16(bh[n], ah[m][ks], acc[m][n], 0, 0, 0);
#pragma unroll
                for (int m = 0; m < 4; ++m)
                    acc[m][n] = __builtin_amdgcn_mfma_f32_16x16x32_bf16(bl[n], ah[m][ks], acc[m][n], 0, 0, 0);
#pragma unroll
                for (int m = 0; m < 4; ++m)
                    acc[m][n] = __builtin_amdgcn_mfma_f32_16x16x32_bf16(bh[n], al[m][ks], acc[m][n], 0, 0, 0);
            }
        }

        // epilogue: lane holds C[m*16+row16][n0 + n*16 + kq*4 + r] (R9-verified)
        float4 bv[4];
#pragma unroll
        for (int n = 0; n < 4; ++n) bv[n] = *(const float4*)(bias + n0 + n * 16 + kq * 4);
#pragma unroll
        for (int m = 0; m < 4; ++m) {
            size_t crow = (size_t)(m0 + m * 16 + row16) * N_NODES + n0;
#pragma unroll
            for (int n = 0; n < 4; ++n) {
                float4 v;
                v.x = acc[m][n][0] + bv[n].x;
                v.y = acc[m][n][1] + bv[n].y;
                v.z = acc[m][n][2] + bv[n].z;
                v.w = acc[m][n][3] + bv[n].w;
                *(float4*)(C + crow + n * 16 + kq * 4) = v;
            }
        }
    }
}

// ---------------- launch ----------------

extern "C" void kernel_launch(void* const* d_in, const int* in_sizes, int n_in,
                              void* d_out, int out_size, void* d_ws, size_t ws_size,
                              hipStream_t stream) {
    const float* x   = (const float*)d_in[0];
    const int*   ei  = (const int*)d_in[1];
    const float* W1  = (const float*)d_in[2];
    const float* b1  = (const float*)d_in[3];
    const float* W2  = (const float*)d_in[4];
    const float* b2  = (const float*)d_in[5];
    const float* W3  = (const float*)d_in[6];
    const float* b3  = (const float*)d_in[7];
    const float* Wfc = (const float*)d_in[8];
    const float* bfc = (const float*)d_in[9];
    float* out = (float*)d_out;

    char* ws = (char*)d_ws;
    int* cnt  = (int*)ws;                   // 16384
    int* rp   = cnt + N_NODES;              // 16385 (+pad)
    int* cur  = rp + N_NODES + 64;          // 16384
    int* eidx = cur + N_NODES;              // E
    float* dinv = (float*)(eidx + E_EDGES); // 16384
    float* t  = dinv + N_NODES;             // N*128 fp32
    float* h  = t + N_NODES * HID;          // N*128 fp32
    unsigned short* Ap = (unsigned short*)t;                    // packed A (8.4 MB, t dead)
    unsigned short* Bp = (unsigned short*)(h + (size_t)N_NODES * HID);  // packed B (8.4 MB)

    k_zero<<<N_NODES / 256, 256, 0, stream>>>(cnt);
    k_count<<<E_EDGES / 256, 256, 0, stream>>>(ei, cnt);
    k_scan<<<1, 1024, 0, stream>>>(cnt, rp, cur, dinv);
    k_fill<<<E_EDGES / 256, 256, 0, stream>>>(ei, cur, eidx);

    // layers
    k_gemm16<<<N_NODES / 2, 256, 0, stream>>>(x, W1, t);
    k_agg<<<N_NODES, 128, 0, stream>>>(t, rp, eidx, dinv, b1, h);
    k_gemm128<<<N_NODES / 64, 256, 0, stream>>>(h, W2, t);
    k_agg<<<N_NODES, 128, 0, stream>>>(t, rp, eidx, dinv, b2, h);
    k_gemm128<<<N_NODES / 64, 256, 0, stream>>>(h, W3, t);
    k_agg<<<N_NODES, 128, 0, stream>>>(t, rp, eidx, dinv, b3, h);

    // prep packed operands
    k_prep_b<<<N_NODES / 64, 256, 0, stream>>>(Wfc, Bp);
    k_prep_a<<<N_NODES / 64, 256, 0, stream>>>(h, Ap);

    // final FC
    k_fc_mfma<<<512, 256, 0, stream>>>(Ap, Bp, bfc, out);
}